// Round 1
// baseline (170.749 us; speedup 1.0000x reference)
//
#include <hip/hip_runtime.h>
#include <math.h>

#define NN        50000
#define BATCH     4
#define LAT       10
#define KNB       32
#define E1OUT     200
#define NCHUNK    8
#define CHUNK     6250    // NN / NCHUNK
#define CHUNK2    3125    // CHUNK / 2 (float2 units)

__device__ __forceinline__ float silu_f(float v) {
    return v / (1.0f + expf(-v));
}

// ---------------- k1: partial dot products for z = x @ enc1_w.T ------------
// grid = 200 rows * 8 chunks; each block reduces one (row, chunk) for 4 batches.
__global__ __launch_bounds__(256) void k1_partial(const float* __restrict__ x,
                                                  const float* __restrict__ w,
                                                  float* __restrict__ partials) {
    const int bx  = blockIdx.x;
    const int r   = bx >> 3;       // enc1 output row 0..199
    const int c   = bx & 7;        // chunk 0..7
    const int tid = threadIdx.x;

    const float2* wr = (const float2*)w + (size_t)r * 25000 + c * CHUNK2;
    const float2* x0 = (const float2*)x + 0 * 25000 + c * CHUNK2;
    const float2* x1 = (const float2*)x + 1 * 25000 + c * CHUNK2;
    const float2* x2 = (const float2*)x + 2 * 25000 + c * CHUNK2;
    const float2* x3 = (const float2*)x + 3 * 25000 + c * CHUNK2;

    float a0 = 0.f, a1 = 0.f, a2 = 0.f, a3 = 0.f;
    for (int j = tid; j < CHUNK2; j += 256) {
        float2 wv = wr[j];
        float2 v0 = x0[j], v1 = x1[j], v2 = x2[j], v3 = x3[j];
        a0 = fmaf(wv.x, v0.x, fmaf(wv.y, v0.y, a0));
        a1 = fmaf(wv.x, v1.x, fmaf(wv.y, v1.y, a1));
        a2 = fmaf(wv.x, v2.x, fmaf(wv.y, v2.y, a2));
        a3 = fmaf(wv.x, v3.x, fmaf(wv.y, v3.y, a3));
    }

    __shared__ float sm[4][256];
    sm[0][tid] = a0; sm[1][tid] = a1; sm[2][tid] = a2; sm[3][tid] = a3;
    __syncthreads();
    for (int s = 128; s > 0; s >>= 1) {
        if (tid < s) {
            sm[0][tid] += sm[0][tid + s];
            sm[1][tid] += sm[1][tid + s];
            sm[2][tid] += sm[2][tid + s];
            sm[3][tid] += sm[3][tid + s];
        }
        __syncthreads();
    }
    if (tid < 4) partials[bx * 4 + tid] = sm[tid][0];
}

// ---------------- k2: reduce partials -> z -> e -> h-MLP -> H table --------
__global__ __launch_bounds__(256) void k2_small(
        const float* __restrict__ partials,
        const float* __restrict__ enc1_b,
        const float* __restrict__ enc2_w, const float* __restrict__ enc2_b,
        const float* __restrict__ h1_w,   const float* __restrict__ h1_b,
        const float* __restrict__ h2_w,   const float* __restrict__ h2_b,
        const float* __restrict__ h3_w,   const float* __restrict__ h3_b,
        float* __restrict__ ws_e, float* __restrict__ ws_h) {
    __shared__ float zs[BATCH][E1OUT];
    __shared__ float es[BATCH][LAT];
    __shared__ float h1s[BATCH][64];
    __shared__ float h2s[BATCH][64];
    const int t = threadIdx.x;

    // z = silu(sum of partials + bias)
    if (t < E1OUT) {
        float a0 = 0.f, a1 = 0.f, a2 = 0.f, a3 = 0.f;
        for (int cc = 0; cc < NCHUNK; ++cc) {
            const float* p = partials + (t * NCHUNK + cc) * 4;
            a0 += p[0]; a1 += p[1]; a2 += p[2]; a3 += p[3];
        }
        float bias = enc1_b[t];
        zs[0][t] = silu_f(a0 + bias);
        zs[1][t] = silu_f(a1 + bias);
        zs[2][t] = silu_f(a2 + bias);
        zs[3][t] = silu_f(a3 + bias);
    }
    __syncthreads();

    // e = z @ enc2_w.T + enc2_b   (4 x 10)
    if (t < BATCH * LAT) {
        int b = t / LAT, l = t % LAT;
        const float* wrow = enc2_w + l * E1OUT;
        float a = 0.f;
        for (int o = 0; o < E1OUT; ++o) a = fmaf(zs[b][o], wrow[o], a);
        a += enc2_b[l];
        es[b][l] = a;
        ws_e[b * LAT + l] = a;
    }
    __syncthreads();

    // h1 = silu(e @ h1_w.T + b)   (4 x 64) ; 256 threads = 4b x 64u
    {
        int b = t >> 6, u = t & 63;
        float a = h1_b[u];
        const float* wrow = h1_w + u * LAT;
        #pragma unroll
        for (int l = 0; l < LAT; ++l) a = fmaf(es[b][l], wrow[l], a);
        h1s[b][u] = silu_f(a);
    }
    __syncthreads();

    // h2 = silu(h1 @ h2_w.T + b)  (4 x 64)
    {
        int b = t >> 6, u = t & 63;
        float a = h2_b[u];
        const float* wrow = h2_w + u * 64;
        for (int j = 0; j < 64; ++j) a = fmaf(h1s[b][j], wrow[j], a);
        h2s[b][u] = silu_f(a);
    }
    __syncthreads();

    // h3 -> sigmoid(0.005*h3)     (4 x 256); thread t = unit u, loop b
    {
        const float* wrow = h3_w + t * 64;
        float bias = h3_b[t];
        #pragma unroll
        for (int b = 0; b < BATCH; ++b) {
            float a = bias;
            for (int j = 0; j < 64; ++j) a = fmaf(h2s[b][j], wrow[j], a);
            ws_h[b * 256 + t] = 1.0f / (1.0f + expf(-0.005f * a));
        }
    }
}

// ---------------- k3: per-point neighbourhood pass -------------------------
// 2 threads per point n: thread handles batches {2*bs, 2*bs+1}.
__global__ __launch_bounds__(256) void k3_main(
        const int*   __restrict__ nid,
        const float* __restrict__ nd,
        const int*   __restrict__ labels,
        const float* __restrict__ dec_w,
        const float* __restrict__ dec_b,
        const float* __restrict__ Bp,
        const float* __restrict__ ws_e,
        const float* __restrict__ ws_h,
        float* __restrict__ out) {
    __shared__ float hs[BATCH * 256];
    __shared__ float es[BATCH * LAT];
    const int tid = threadIdx.x;
    for (int i = tid; i < BATCH * 256; i += 256) hs[i] = ws_h[i];
    if (tid < BATCH * LAT) es[tid] = ws_e[tid];
    __syncthreads();

    const int gid = blockIdx.x * 256 + tid;
    const int n   = gid >> 1;
    const int bs  = gid & 1;                 // batch pair selector
    if (n >= NN) return;

    const float Bv = Bp[0];
    const int   c  = labels[n];

    // invw2[bb][l] = 1 / ((1-H/2)^(l+1) * B)^2
    float invw2[2][LAT];
    #pragma unroll
    for (int bb = 0; bb < 2; ++bb) {
        const int b = bs * 2 + bb;
        const float H    = hs[b * 256 + c];
        const float base = 1.0f - 0.5f * H;
        float cur = base;
        #pragma unroll
        for (int l = 0; l < LAT; ++l) {
            float wv = cur * Bv;
            invw2[bb][l] = 1.0f / (wv * wv);
            cur *= base;
        }
    }

    float num[2][LAT], den[2][LAT];
    #pragma unroll
    for (int bb = 0; bb < 2; ++bb)
        #pragma unroll
        for (int l = 0; l < LAT; ++l) { num[bb][l] = 0.f; den[bb][l] = 0.f; }

    const int4*   nid4 = (const int4*)(nid + (size_t)n * KNB);
    const float4* nd4  = (const float4*)(nd  + (size_t)n * KNB);
    const float2* dw2  = (const float2*)dec_w;

    #pragma unroll
    for (int kk = 0; kk < KNB / 4; ++kk) {
        const int4   id4 = nid4[kk];
        const float4 dd4 = nd4[kk];
        const int   ids[4] = {id4.x, id4.y, id4.z, id4.w};
        const float dsv[4] = {dd4.x, dd4.y, dd4.z, dd4.w};
        #pragma unroll
        for (int q = 0; q < 4; ++q) {
            const float d2 = dsv[q] * dsv[q];
            const float2* brow = dw2 + (size_t)ids[q] * 5;
            const float2 b01 = brow[0], b23 = brow[1], b45 = brow[2],
                         b67 = brow[3], b89 = brow[4];
            const float bas[LAT] = {b01.x, b01.y, b23.x, b23.y, b45.x,
                                    b45.y, b67.x, b67.y, b89.x, b89.y};
            #pragma unroll
            for (int bb = 0; bb < 2; ++bb) {
                #pragma unroll
                for (int l = 0; l < LAT; ++l) {
                    float t = fmaf(-d2, invw2[bb][l], 1.0f);
                    t = fmaxf(t, 0.0f);
                    den[bb][l] += t;
                    num[bb][l]  = fmaf(t, bas[l], num[bb][l]);
                }
            }
        }
    }

    const float dbv = dec_b[n];
    #pragma unroll
    for (int bb = 0; bb < 2; ++bb) {
        const int b = bs * 2 + bb;
        float acc = 0.f;
        #pragma unroll
        for (int l = 0; l < LAT; ++l)
            acc += es[b * LAT + l] * (num[bb][l] / den[bb][l]);
        out[(size_t)b * NN + n] = acc + dbv;
    }
}

extern "C" void kernel_launch(void* const* d_in, const int* in_sizes, int n_in,
                              void* d_out, int out_size, void* d_ws, size_t ws_size,
                              hipStream_t stream) {
    const float* x      = (const float*)d_in[0];
    const int*   nid    = (const int*)  d_in[1];
    const float* nd     = (const float*)d_in[2];
    const int*   labels = (const int*)  d_in[3];
    const float* enc1_w = (const float*)d_in[4];
    const float* enc1_b = (const float*)d_in[5];
    const float* enc2_w = (const float*)d_in[6];
    const float* enc2_b = (const float*)d_in[7];
    const float* dec_w  = (const float*)d_in[8];
    const float* dec_b  = (const float*)d_in[9];
    const float* h1_w   = (const float*)d_in[10];
    const float* h1_b   = (const float*)d_in[11];
    const float* h2_w   = (const float*)d_in[12];
    const float* h2_b   = (const float*)d_in[13];
    const float* h3_w   = (const float*)d_in[14];
    const float* h3_b   = (const float*)d_in[15];
    const float* Bp     = (const float*)d_in[16];

    float* ws       = (float*)d_ws;
    float* partials = ws;            // 1600*4 = 6400 floats
    float* ws_e     = ws + 6400;     // 40 floats
    float* ws_h     = ws + 6440;     // 1024 floats
    float* out      = (float*)d_out;

    k1_partial<<<E1OUT * NCHUNK, 256, 0, stream>>>(x, enc1_w, partials);
    k2_small<<<1, 256, 0, stream>>>(partials, enc1_b, enc2_w, enc2_b,
                                    h1_w, h1_b, h2_w, h2_b, h3_w, h3_b,
                                    ws_e, ws_h);
    const int k3_threads = NN * 2;
    k3_main<<<(k3_threads + 255) / 256, 256, 0, stream>>>(
        nid, nd, labels, dec_w, dec_b, Bp, ws_e, ws_h, out);
}